// Round 2
// baseline (147.974 us; speedup 1.0000x reference)
//
#include <hip/hip_runtime.h>

#define NPTS 131072
#define PRE_BLOCKS 16

typedef __attribute__((ext_vector_type(8))) short short8;
typedef __attribute__((ext_vector_type(4))) float f32x4;

// ---------- d_ws layout (f32 dword indices) ----------
constexpr int OFF_SW1 = 0;      // 1024 SW1 TRANSPOSED [c*32+e] (gate recompute)
constexpr int OFF_BNS = 1024;   // 32
constexpr int OFF_BNH = 1056;   // 32
constexpr int OFF_SW2 = 1088;   // 32
constexpr int OFF_B2  = 1120;   // 1
constexpr int OFF_QGB = 1121;   // 19
constexpr int OFF_QMB = 1140;   // 3
constexpr int OFF_BB  = 1143;   // 19
constexpr int OFF_CV  = 1162;   // 19
constexpr int OFF_MVB = 1181;   // 57 [m*19+j]
constexpr int EGVB    = 1240;   // 380 = 19x20 padded GVB (16B-aligned)
constexpr int FRAGH   = 1620;   // 1280 dwords: B-frags hi [5][64][8] bf16
constexpr int FRAGL   = 2900;   // 512  dwords: B-frags lo [2][64][8] bf16 (SW1)

#define CONST_AS __attribute__((address_space(4)))
__device__ __forceinline__ const CONST_AS float* to_const(const float* p) {
    return (const CONST_AS float*)p;
}
__device__ __forceinline__ unsigned b16r(float x) {
    unsigned u = __float_as_uint(x);
    return (u + 0x7fffu + ((u >> 16) & 1u)) >> 16;
}
__device__ __forceinline__ float fromb(unsigned h) {
    return __uint_as_float(h << 16);
}
// inverse fragment map: value for (e=k-dim, col) -> FH[(T*64+l)*8+jj]
__device__ __forceinline__ int fragidx(int e, int col) {
    int T = col >> 4, l = (col & 15) + ((e >> 3) << 4), jj = e & 7;
    return (T * 64 + l) * 8 + jj;
}

// =====================================================================
// Parallel precompute: ONE launch, PRE_BLOCKS blocks. Every block
// redundantly computes the tiny stage-A/B intermediates in its own LDS
// (~94K FMA/block, trivial); the ~5.1K global-output items are
// partitioned across blocks by a strided loop. Restores multi-CU
// parallelism that the single-block pre_all lost, while keeping the
// single-launch win over pre_a/b/c.
// =====================================================================
__global__ __launch_bounds__(256) void pre_par(
    const float* __restrict__ z,
    const float* __restrict__ sw1,
    const float* __restrict__ bn_gamma, const float* __restrict__ bn_beta,
    const float* __restrict__ bn_mean,  const float* __restrict__ bn_var,
    const float* __restrict__ sw2,      const float* __restrict__ sb2,
    const float* __restrict__ wq, const float* __restrict__ bq,
    const float* __restrict__ wk, const float* __restrict__ wv,
    const float* __restrict__ bv,
    const float* __restrict__ wo, const float* __restrict__ bo,
    const float* __restrict__ wt, const float* __restrict__ bt,
    const float* __restrict__ wout, const float* __restrict__ bout,
    const float* __restrict__ wgen, const float* __restrict__ bgen,
    float* __restrict__ W)
{
    __shared__ float XA2s[608], XGs[608], XMKs[96], XMVs[96];
    __shared__ float XGKs[608], XGVs[608], XBs[608];
    const int tid = threadIdx.x;
    unsigned short* FH = (unsigned short*)(W + FRAGH);
    unsigned short* FL = (unsigned short*)(W + FRAGL);

    // ---- stage A (redundant per block): XA2, XG, XMK, XMV ----
    for (int i = tid; i < 1312; i += 256) {
        if (i < 608) {                        // XA2[e*19+j]
            int e = i / 19, j = i % 19;
            float a2 = 0.f;
            for (int d = 0; d < 32; ++d) a2 += wt[(32 + e)*32 + d] * wout[d*19 + j];
            XA2s[i] = a2;
        } else if (i < 1216) {                // XG[k*32+e]
            int t = i - 608, k = t >> 5, e = t & 31;
            float g = bgen[e];
            for (int d = 0; d < 16; ++d) g += z[d] * wgen[d*32 + e];
            XGs[t] = g + wgen[(16 + k)*32 + e];
        } else {                              // XMK/XMV [m*32+c]
            int t = i - 1216, m = t >> 5, c = t & 31;
            float a = 0.f, b = 0.f;
            for (int e = 0; e < 32; ++e) {
                float wsr = wgen[(35 + m)*32 + e];
                a += wsr * wk[e*32 + c];
                b += wsr * wv[e*32 + c];
            }
            XMKs[t] = a; XMVs[t] = b;
        }
    }
    __syncthreads();
    // ---- stage B (redundant per block): XGK, XGV, XB ----
    for (int i = tid; i < 1216; i += 256) {
        if (i < 608) {                        // Gk, Gv  [k*32+c]
            int k = i >> 5, c = i & 31;
            float a = 0.f, b = 0.f;
            for (int e = 0; e < 32; ++e) {
                float g = XGs[k*32 + e];
                a += g * wk[e*32 + c];
                b += g * wv[e*32 + c];
            }
            XGKs[i] = a; XGVs[i] = b;
        } else {                              // XB[c*19+j] = wo @ A2
            int t2 = i - 608, c = t2 / 19, j = t2 % 19;
            float a = 0.f;
            for (int d = 0; d < 32; ++d) a += wo[c*32 + d] * XA2s[d*19 + j];
            XBs[t2] = a;
        }
    }
    __syncthreads();
    // ---- global outputs: 5138 items partitioned across all blocks ----
    for (int i = blockIdx.x * 256 + tid; i < 5138; i += 256 * PRE_BLOCKS) {
        if (i < 1024) {                       // SW1T[c*32+e] = sw1[e*32+c]
            W[OFF_SW1 + i] = sw1[(i & 31) * 32 + (i >> 5)];
        } else if (i < 1632) {                // A1 -> fragment col 51+j
            int t = i - 1024, e = t / 19, j = t % 19;
            float a1 = 0.f;
            for (int d = 0; d < 32; ++d) a1 += wt[e*32 + d] * wout[d*19 + j];
            FH[fragidx(e, 51 + j)] = (unsigned short)b16r(a1);
        } else if (i < 1664) {                // BN fold + SW2
            int t = i - 1632;
            float scale = bn_gamma[t] / sqrtf(bn_var[t] + 1e-4f);
            W[OFF_BNS + t] = scale;
            W[OFF_BNH + t] = bn_beta[t] - bn_mean[t] * scale;
            W[OFF_SW2 + t] = sw2[t];
        } else if (i < 1683) {                // BB
            int t = i - 1664;
            float a = bout[t];
            for (int d = 0; d < 32; ++d) a += bt[d] * wout[d*19 + t];
            W[OFF_BB + t] = a;
        } else if (i == 1683) {
            W[OFF_B2] = sb2[0];
        } else if (i < 2708) {                // SW1 hi fragments (tiles 0-1)
            int idx = i - 1684;
            int T = idx >> 9, rem = idx & 511, l = rem >> 3, j = rem & 7;
            int e = ((l >> 4) << 3) + j, col = 16*T + (l & 15);
            FH[(T*64 + l)*8 + j] = (unsigned short)b16r(sw1[e*32 + col]);
        } else if (i < 3732) {                // SW1 lo fragments
            int idx = i - 2708;
            int T = idx >> 9, rem = idx & 511, l = rem >> 3, j = rem & 7;
            int e = ((l >> 4) << 3) + j, col = 16*T + (l & 15);
            float v = sw1[e*32 + col];
            FL[(T*64 + l)*8 + j] = (unsigned short)b16r(v - fromb(b16r(v)));
        } else if (i < 3956) {                // pad cols 73..79 of tile 4 = 0
            int idx = i - 3732;
            int col = 73 + idx / 32, rem = idx & 31, qq = rem >> 3, j2 = rem & 7;
            int l = (col & 15) + (qq << 4);
            FH[(4*64 + l)*8 + j2] = 0;
        } else if (i < 4052) {                // QM[e][m] -> fragment col 70+m
            int t2 = i - 3956, e = t2 / 3, m = t2 % 3;
            float a = 0.f;
            for (int c = 0; c < 32; ++c) a += wq[e*32 + c] * XMKs[m*32 + c];
            FH[fragidx(e, 70 + m)] = (unsigned short)b16r(a);
        } else if (i < 4055) {                // QMB[m]
            int m = i - 4052;
            float a = 0.f;
            for (int c = 0; c < 32; ++c) a += bq[c] * XMKs[m*32 + c];
            W[OFF_QMB + m] = a;
        } else if (i < 4663) {                // QG[e][k] -> fragment col 32+k
            int t2 = i - 4055, e = t2 / 19, k = t2 % 19;
            float a = 0.f;
            for (int c = 0; c < 32; ++c) a += wq[e*32 + c] * XGKs[k*32 + c];
            FH[fragidx(e, 32 + k)] = (unsigned short)b16r(a);
        } else if (i < 4682) {                // QGB[k]
            int k = i - 4663;
            float a = 0.f;
            for (int c = 0; c < 32; ++c) a += bq[c] * XGKs[k*32 + c];
            W[OFF_QGB + k] = a;
        } else if (i < 5043) {                // EGVB[k*20+j]
            int t2 = i - 4682, k = t2 / 19, j = t2 % 19;
            float a = 0.f;
            for (int c = 0; c < 32; ++c) a += XGVs[k*32 + c] * XBs[c*19 + j];
            W[EGVB + k*20 + j] = a;
        } else if (i < 5062) {                // EGVB pad col
            int k = i - 5043;
            W[EGVB + k*20 + 19] = 0.f;
        } else if (i < 5119) {                // MVB[m*19+j]
            int t2 = i - 5062, m = t2 / 19, j = t2 % 19;
            float a = 0.f;
            for (int c = 0; c < 32; ++c) a += XMVs[m*32 + c] * XBs[c*19 + j];
            W[OFF_MVB + t2] = a;
        } else {                              // CV[j]
            int j = i - 5119;
            float a = 0.f;
            for (int c = 0; c < 32; ++c) a += bv[c] * XBs[c*19 + j];
            for (int d = 0; d < 32; ++d) a += bo[d] * XA2s[d*19 + j];
            W[OFF_CV + j] = a;
        }
    }
}

// =====================================================================
// Main kernel — unchanged from round 1 (isolate the pre change).
// =====================================================================
__global__ __launch_bounds__(256, 3) void main_k(
    const float* __restrict__ feat,
    const float* __restrict__ sflow,
    const float* __restrict__ cpred,
    const float* __restrict__ Wg,
    float* __restrict__ out)
{
    const CONST_AS float* W = to_const(Wg);
    const int t = threadIdx.x, lane = t & 63, wvi = t >> 6;
    const int pblk = blockIdx.x * 256;
    const int n15 = lane & 15, q = lane >> 4;

    __shared__ __align__(16) unsigned short OH[41 * 264];   // 21648 B; f32 out-slab overlay
    __shared__ __align__(16) float CP[256 * 19];            // 19456 B cp slab
    __shared__ __align__(16) float GV[380];                 // 1520 B
    __shared__ __align__(16) float SG[256];                 // 1024 B gate sums

    // ---- hoisted global loads: in flight during cpred staging ----
    float4 fva[4], fvb[4];
#pragma unroll
    for (int tile = 0; tile < 4; ++tile) {
        const float* fr = feat + (long)(pblk + wvi*64 + tile*16 + n15) * 32 + q*8;
        fva[tile] = *(const float4*)fr;
        fvb[tile] = *(const float4*)(fr + 4);
    }
    const short8* FH8 = (const short8*)(Wg + FRAGH);
    const short8* FL8 = (const short8*)(Wg + FRAGL);
    short8 bh0 = FH8[0*64 + lane], bh1 = FH8[1*64 + lane];
    short8 bh2 = FH8[2*64 + lane], bh3 = FH8[3*64 + lane];
    short8 bh4 = FH8[4*64 + lane];
    short8 bl0 = FL8[0*64 + lane], bl1 = FL8[1*64 + lane];

    const long p = pblk + t;
    float s0 = sflow[p*3 + 0], s1 = sflow[p*3 + 1], s2 = sflow[p*3 + 2];

    // per-lane BN/gate constants for c = n15 and c = 16+n15
    float bns0 = W[OFF_BNS + n15],      bnh0 = W[OFF_BNH + n15],      w20 = W[OFF_SW2 + n15];
    float bns1 = W[OFF_BNS + 16 + n15], bnh1 = W[OFF_BNH + 16 + n15], w21 = W[OFF_SW2 + 16 + n15];

    if (t < 95) ((float4*)GV)[t] = ((const float4*)(Wg + EGVB))[t];

    // ---- phase 0: stage cpred slab (coalesced) ----
    {
        const float4* src = (const float4*)(cpred + (long)pblk * 19);
        float4* dst = (float4*)CP;
        dst[t] = src[t];
        dst[256 + t] = src[256 + t];
        dst[512 + t] = src[512 + t];
        dst[768 + t] = src[768 + t];
        if (t < 192) dst[1024 + t] = src[1024 + t];
    }
    __syncthreads();                                   // [1]
    {
        float cp[19];
#pragma unroll
        for (int k = 0; k < 19; ++k) cp[k] = CP[t*19 + k];
        float m1 = cp[0];
#pragma unroll
        for (int k = 1; k < 19; ++k) m1 = fmaxf(m1, cp[k]);
        float sum1 = 0.f;
#pragma unroll
        for (int k = 0; k < 19; ++k) { cp[k] = __expf(cp[k] - m1); sum1 += cp[k]; }
        float r1 = 1.f / sum1;
#pragma unroll
        for (int k = 0; k < 19; ++k) CP[t*19 + k] = cp[k] * r1;   // own row: no barrier
    }

    // ---- phase 1: MFMA, 4 tiles of 16 points per wave ----
#pragma unroll
    for (int tile = 0; tile < 4; ++tile) {
        const int p0 = wvi*64 + tile*16;
        float xv[8];
        xv[0]=fva[tile].x; xv[1]=fva[tile].y; xv[2]=fva[tile].z; xv[3]=fva[tile].w;
        xv[4]=fvb[tile].x; xv[5]=fvb[tile].y; xv[6]=fvb[tile].z; xv[7]=fvb[tile].w;
        short8 ah, al;
#pragma unroll
        for (int j = 0; j < 8; ++j) {
            unsigned h = b16r(xv[j]);
            ah[j] = (short)h;
            al[j] = (short)b16r(xv[j] - fromb(h));
        }
        f32x4 z4 = {0.f, 0.f, 0.f, 0.f};
        f32x4 aH0, aH1, a2_, a3_, a4_;
        aH0 = __builtin_amdgcn_mfma_f32_16x16x32_bf16(ah, bh0, z4, 0, 0, 0);
        aH0 = __builtin_amdgcn_mfma_f32_16x16x32_bf16(ah, bl0, aH0, 0, 0, 0);
        aH0 = __builtin_amdgcn_mfma_f32_16x16x32_bf16(al, bh0, aH0, 0, 0, 0);
        aH1 = __builtin_amdgcn_mfma_f32_16x16x32_bf16(ah, bh1, z4, 0, 0, 0);
        aH1 = __builtin_amdgcn_mfma_f32_16x16x32_bf16(ah, bl1, aH1, 0, 0, 0);
        aH1 = __builtin_amdgcn_mfma_f32_16x16x32_bf16(al, bh1, aH1, 0, 0, 0);
        a2_ = __builtin_amdgcn_mfma_f32_16x16x32_bf16(ah, bh2, z4, 0, 0, 0);
        a3_ = __builtin_amdgcn_mfma_f32_16x16x32_bf16(ah, bh3, z4, 0, 0, 0);
        a4_ = __builtin_amdgcn_mfma_f32_16x16x32_bf16(ah, bh4, z4, 0, 0, 0);

        // gate: h = relu(a*bns+bnh), partial = h*w2 for c=n15 and 16+n15,
        // then sum across the 16 c-lanes (same q) -> full 32-c gate sum
        float g0, g1, g2, g3;
        {
            float h0, h1;
            h0 = fmaxf(fmaf(aH0[0], bns0, bnh0), 0.f);
            h1 = fmaxf(fmaf(aH1[0], bns1, bnh1), 0.f);
            g0 = fmaf(h0, w20, h1 * w21);
            h0 = fmaxf(fmaf(aH0[1], bns0, bnh0), 0.f);
            h1 = fmaxf(fmaf(aH1[1], bns1, bnh1), 0.f);
            g1 = fmaf(h0, w20, h1 * w21);
            h0 = fmaxf(fmaf(aH0[2], bns0, bnh0), 0.f);
            h1 = fmaxf(fmaf(aH1[2], bns1, bnh1), 0.f);
            g2 = fmaf(h0, w20, h1 * w21);
            h0 = fmaxf(fmaf(aH0[3], bns0, bnh0), 0.f);
            h1 = fmaxf(fmaf(aH1[3], bns1, bnh1), 0.f);
            g3 = fmaf(h0, w20, h1 * w21);
        }
#pragma unroll
        for (int m = 1; m < 16; m <<= 1) {
            g0 += __shfl_xor(g0, m, 64);
            g1 += __shfl_xor(g1, m, 64);
            g2 += __shfl_xor(g2, m, 64);
            g3 += __shfl_xor(g3, m, 64);
        }
        if (n15 == 0)
            *(float4*)&SG[p0 + q*4] = make_float4(g0, g1, g2, g3);

        {
            unsigned d0, d1;
            d0 = b16r(a2_[0]) | (b16r(a2_[1]) << 16);
            d1 = b16r(a2_[2]) | (b16r(a2_[3]) << 16);
            *(uint2*)&OH[(n15) * 264 + p0 + q*4] = make_uint2(d0, d1);
            d0 = b16r(a3_[0]) | (b16r(a3_[1]) << 16);
            d1 = b16r(a3_[2]) | (b16r(a3_[3]) << 16);
            *(uint2*)&OH[(16 + n15) * 264 + p0 + q*4] = make_uint2(d0, d1);
            if (n15 <= 8) {
                d0 = b16r(a4_[0]) | (b16r(a4_[1]) << 16);
                d1 = b16r(a4_[2]) | (b16r(a4_[3]) << 16);
                *(uint2*)&OH[(32 + n15) * 264 + p0 + q*4] = make_uint2(d0, d1);
            }
        }
    }
    __syncthreads();                                   // [2]

    // =========== phase 2: epilogue, thread t = point p ===========
    bool tmask = (s0 != 0.f) | (s1 != 0.f) | (s2 != 0.f);

    const float TH = 1.3862943611198906f;   // ln(4): sigmoid<0.8
    float sacc = SG[t] + W[OFF_B2];
    // margin safety net: exact f32 recompute for near-threshold points
    bool nearthr = fabsf(sacc - TH) < 1e-3f;
    if (__ballot(nearthr) != 0ULL) {
        float f[32];
        const float4* fp4 = (const float4*)(feat + p*32);
#pragma unroll
        for (int g = 0; g < 8; ++g) {
            float4 v = fp4[g];
            f[g*4+0]=v.x; f[g*4+1]=v.y; f[g*4+2]=v.z; f[g*4+3]=v.w;
        }
        float sr = W[OFF_B2];
        for (int c = 0; c < 32; ++c) {
            float a = 0.f;
#pragma unroll
            for (int e = 0; e < 32; ++e) a = fmaf(f[e], W[OFF_SW1 + c*32 + e], a);
            float h = fmaxf(fmaf(a, W[OFF_BNS + c], W[OFF_BNH + c]), 0.f);
            sr = fmaf(h, W[OFF_SW2 + c], sr);
        }
        sacc = nearthr ? sr : sacc;
    }
    bool valid = tmask && (sacc < TH);

    // ---- logits / qs from mfma U ----
    float qm0 = fromb(OH[38*264 + t]) + W[OFF_QMB + 0];
    float qm1 = fromb(OH[39*264 + t]) + W[OFF_QMB + 1];
    float qm2 = fromb(OH[40*264 + t]) + W[OFF_QMB + 2];
    float qs = s0*qm0 + s1*qm1 + s2*qm2;

    float cp[19];
#pragma unroll
    for (int k = 0; k < 19; ++k) cp[k] = CP[t*19 + k];

    const float RS = 0.17677669529663687f;  // 1/sqrt(32)
    float l[19];
#pragma unroll
    for (int k = 0; k < 19; ++k)
        l[k] = (cp[k] * (fromb(OH[k*264 + t]) + W[OFF_QGB + k] + qs)) * RS;

    float m2 = l[0];
#pragma unroll
    for (int k = 1; k < 19; ++k) m2 = fmaxf(m2, l[k]);
    float sum2 = 0.f;
#pragma unroll
    for (int k = 0; k < 19; ++k) { l[k] = __expf(l[k] - m2); sum2 += l[k]; }
    float r2 = 1.f / sum2;
    float Sw = 0.f;
#pragma unroll
    for (int k = 0; k < 19; ++k) { l[k] = l[k] * r2 * cp[k]; Sw += l[k]; }

    // ---- o = U_A1 + BB;  a2 = CV + Sw*(sf@MVB) + w@GVB ----
    float rv[19];
    float c0 = Sw * s0, c1 = Sw * s1, c2 = Sw * s2;
    float vg = valid ? 1.f : 0.f;
    float a2v[19];
#pragma unroll
    for (int j = 0; j < 19; ++j)
        a2v[j] = W[OFF_CV + j] + c0 * W[OFF_MVB + j]
               + c1 * W[OFF_MVB + 19 + j] + c2 * W[OFF_MVB + 38 + j];
#pragma unroll
    for (int k = 0; k < 19; ++k) {
        float lk = l[k];
#pragma unroll
        for (int j = 0; j < 19; ++j) a2v[j] = fmaf(lk, GV[k*20 + j], a2v[j]);
    }
#pragma unroll
    for (int j = 0; j < 19; ++j)
        rv[j] = fmaf(vg, a2v[j], fromb(OH[(19 + j)*264 + t]) + W[OFF_BB + j]);

    // ---- phase 3: stage out rows (overlay on OH) -> coalesced float4 ----
    __syncthreads();                                   // [3] all OH reads done
    float* SLAB = (float*)OH;
#pragma unroll
    for (int j = 0; j < 19; ++j) SLAB[t*19 + j] = rv[j];
    __syncthreads();                                   // [4]
    {
        const float4* src = (const float4*)SLAB;
        float4* dst = (float4*)(out + (long)pblk * 19);
        dst[t] = src[t];
        dst[256 + t] = src[256 + t];
        dst[512 + t] = src[512 + t];
        dst[768 + t] = src[768 + t];
        if (t < 192) dst[1024 + t] = src[1024 + t];
    }
}

// =====================================================================
extern "C" void kernel_launch(void* const* d_in, const int* in_sizes, int n_in,
                              void* d_out, int out_size, void* d_ws, size_t ws_size,
                              hipStream_t stream) {
    const float* feat  = (const float*)d_in[0];
    const float* sflow = (const float*)d_in[1];
    const float* cpred = (const float*)d_in[2];
    const float* z     = (const float*)d_in[3];
    const float* sw1   = (const float*)d_in[4];
    const float* bn_g  = (const float*)d_in[5];
    const float* bn_b  = (const float*)d_in[6];
    const float* bn_m  = (const float*)d_in[7];
    const float* bn_v  = (const float*)d_in[8];
    const float* sw2   = (const float*)d_in[9];
    const float* sb2   = (const float*)d_in[10];
    const float* wq    = (const float*)d_in[11];
    const float* bq    = (const float*)d_in[12];
    const float* wk    = (const float*)d_in[13];
    const float* bk    = (const float*)d_in[14];  (void)bk;
    const float* wv    = (const float*)d_in[15];
    const float* bv    = (const float*)d_in[16];
    const float* wo    = (const float*)d_in[17];
    const float* bo    = (const float*)d_in[18];
    const float* wt    = (const float*)d_in[19];
    const float* bt    = (const float*)d_in[20];
    const float* wout  = (const float*)d_in[21];
    const float* bout  = (const float*)d_in[22];
    const float* wgen  = (const float*)d_in[23];
    const float* bgen  = (const float*)d_in[24];

    float* W = (float*)d_ws;

    hipLaunchKernelGGL(pre_par, dim3(PRE_BLOCKS), dim3(256), 0, stream,
                       z, sw1, bn_g, bn_b, bn_m, bn_v, sw2, sb2,
                       wq, bq, wk, wv, bv, wo, bo, wt, bt, wout, bout,
                       wgen, bgen, W);

    hipLaunchKernelGGL(main_k, dim3(512), dim3(256), 0, stream,
                       feat, sflow, cpred, W, (float*)d_out);
}

// Round 3
// 143.975 us; speedup vs baseline: 1.0278x; 1.0278x over previous
//
#include <hip/hip_runtime.h>

#define NPTS 131072
#define PRE_BLOCKS 16

typedef __attribute__((ext_vector_type(8))) short short8;
typedef __attribute__((ext_vector_type(4))) float f32x4;

// ---------- d_ws layout (f32 dword indices) ----------
constexpr int OFF_SW1 = 0;      // 1024 SW1 TRANSPOSED [c*32+e] (gate recompute)
constexpr int OFF_BNS = 1024;   // 32
constexpr int OFF_BNH = 1056;   // 32
constexpr int OFF_SW2 = 1088;   // 32
constexpr int OFF_B2  = 1120;   // 1
constexpr int OFF_QGB = 1121;   // 19
constexpr int OFF_QMB = 1140;   // 3
constexpr int OFF_BB  = 1143;   // 19
constexpr int OFF_CV  = 1162;   // 19
constexpr int OFF_MVB = 1181;   // 57 [m*19+j]
constexpr int EGVB    = 1240;   // 380 = 19x20 padded GVB (16B-aligned)
constexpr int FRAGH   = 1620;   // 1280 dwords: B-frags hi [5][64][8] bf16
constexpr int FRAGL   = 2900;   // 512  dwords: B-frags lo [2][64][8] bf16 (SW1)

#define CONST_AS __attribute__((address_space(4)))
__device__ __forceinline__ const CONST_AS float* to_const(const float* p) {
    return (const CONST_AS float*)p;
}
__device__ __forceinline__ unsigned b16r(float x) {
    unsigned u = __float_as_uint(x);
    return (u + 0x7fffu + ((u >> 16) & 1u)) >> 16;
}
__device__ __forceinline__ float fromb(unsigned h) {
    return __uint_as_float(h << 16);
}
// inverse fragment map: value for (e=k-dim, col) -> FH[(T*64+l)*8+jj]
__device__ __forceinline__ int fragidx(int e, int col) {
    int T = col >> 4, l = (col & 15) + ((e >> 3) << 4), jj = e & 7;
    return (T * 64 + l) * 8 + jj;
}

// =====================================================================
// Parallel precompute: ONE launch, PRE_BLOCKS blocks. Every block
// redundantly computes the tiny stage-A/B intermediates in its own LDS;
// the ~5.1K global-output items are partitioned across blocks.
// =====================================================================
__global__ __launch_bounds__(256) void pre_par(
    const float* __restrict__ z,
    const float* __restrict__ sw1,
    const float* __restrict__ bn_gamma, const float* __restrict__ bn_beta,
    const float* __restrict__ bn_mean,  const float* __restrict__ bn_var,
    const float* __restrict__ sw2,      const float* __restrict__ sb2,
    const float* __restrict__ wq, const float* __restrict__ bq,
    const float* __restrict__ wk, const float* __restrict__ wv,
    const float* __restrict__ bv,
    const float* __restrict__ wo, const float* __restrict__ bo,
    const float* __restrict__ wt, const float* __restrict__ bt,
    const float* __restrict__ wout, const float* __restrict__ bout,
    const float* __restrict__ wgen, const float* __restrict__ bgen,
    float* __restrict__ W)
{
    __shared__ float XA2s[608], XGs[608], XMKs[96], XMVs[96];
    __shared__ float XGKs[608], XGVs[608], XBs[608];
    const int tid = threadIdx.x;
    unsigned short* FH = (unsigned short*)(W + FRAGH);
    unsigned short* FL = (unsigned short*)(W + FRAGL);

    // ---- stage A (redundant per block): XA2, XG, XMK, XMV ----
    for (int i = tid; i < 1312; i += 256) {
        if (i < 608) {                        // XA2[e*19+j]
            int e = i / 19, j = i % 19;
            float a2 = 0.f;
            for (int d = 0; d < 32; ++d) a2 += wt[(32 + e)*32 + d] * wout[d*19 + j];
            XA2s[i] = a2;
        } else if (i < 1216) {                // XG[k*32+e]
            int t = i - 608, k = t >> 5, e = t & 31;
            float g = bgen[e];
            for (int d = 0; d < 16; ++d) g += z[d] * wgen[d*32 + e];
            XGs[t] = g + wgen[(16 + k)*32 + e];
        } else {                              // XMK/XMV [m*32+c]
            int t = i - 1216, m = t >> 5, c = t & 31;
            float a = 0.f, b = 0.f;
            for (int e = 0; e < 32; ++e) {
                float wsr = wgen[(35 + m)*32 + e];
                a += wsr * wk[e*32 + c];
                b += wsr * wv[e*32 + c];
            }
            XMKs[t] = a; XMVs[t] = b;
        }
    }
    __syncthreads();
    // ---- stage B (redundant per block): XGK, XGV, XB ----
    for (int i = tid; i < 1216; i += 256) {
        if (i < 608) {                        // Gk, Gv  [k*32+c]
            int k = i >> 5, c = i & 31;
            float a = 0.f, b = 0.f;
            for (int e = 0; e < 32; ++e) {
                float g = XGs[k*32 + e];
                a += g * wk[e*32 + c];
                b += g * wv[e*32 + c];
            }
            XGKs[i] = a; XGVs[i] = b;
        } else {                              // XB[c*19+j] = wo @ A2
            int t2 = i - 608, c = t2 / 19, j = t2 % 19;
            float a = 0.f;
            for (int d = 0; d < 32; ++d) a += wo[c*32 + d] * XA2s[d*19 + j];
            XBs[t2] = a;
        }
    }
    __syncthreads();
    // ---- global outputs: 5138 items partitioned across all blocks ----
    for (int i = blockIdx.x * 256 + tid; i < 5138; i += 256 * PRE_BLOCKS) {
        if (i < 1024) {                       // SW1T[c*32+e] = sw1[e*32+c]
            W[OFF_SW1 + i] = sw1[(i & 31) * 32 + (i >> 5)];
        } else if (i < 1632) {                // A1 -> fragment col 51+j
            int t = i - 1024, e = t / 19, j = t % 19;
            float a1 = 0.f;
            for (int d = 0; d < 32; ++d) a1 += wt[e*32 + d] * wout[d*19 + j];
            FH[fragidx(e, 51 + j)] = (unsigned short)b16r(a1);
        } else if (i < 1664) {                // BN fold + SW2
            int t = i - 1632;
            float scale = bn_gamma[t] / sqrtf(bn_var[t] + 1e-4f);
            W[OFF_BNS + t] = scale;
            W[OFF_BNH + t] = bn_beta[t] - bn_mean[t] * scale;
            W[OFF_SW2 + t] = sw2[t];
        } else if (i < 1683) {                // BB
            int t = i - 1664;
            float a = bout[t];
            for (int d = 0; d < 32; ++d) a += bt[d] * wout[d*19 + t];
            W[OFF_BB + t] = a;
        } else if (i == 1683) {
            W[OFF_B2] = sb2[0];
        } else if (i < 2708) {                // SW1 hi fragments (tiles 0-1)
            int idx = i - 1684;
            int T = idx >> 9, rem = idx & 511, l = rem >> 3, j = rem & 7;
            int e = ((l >> 4) << 3) + j, col = 16*T + (l & 15);
            FH[(T*64 + l)*8 + j] = (unsigned short)b16r(sw1[e*32 + col]);
        } else if (i < 3732) {                // SW1 lo fragments
            int idx = i - 2708;
            int T = idx >> 9, rem = idx & 511, l = rem >> 3, j = rem & 7;
            int e = ((l >> 4) << 3) + j, col = 16*T + (l & 15);
            float v = sw1[e*32 + col];
            FL[(T*64 + l)*8 + j] = (unsigned short)b16r(v - fromb(b16r(v)));
        } else if (i < 3956) {                // pad cols 73..79 of tile 4 = 0
            int idx = i - 3732;
            int col = 73 + idx / 32, rem = idx & 31, qq = rem >> 3, j2 = rem & 7;
            int l = (col & 15) + (qq << 4);
            FH[(4*64 + l)*8 + j2] = 0;
        } else if (i < 4052) {                // QM[e][m] -> fragment col 70+m
            int t2 = i - 3956, e = t2 / 3, m = t2 % 3;
            float a = 0.f;
            for (int c = 0; c < 32; ++c) a += wq[e*32 + c] * XMKs[m*32 + c];
            FH[fragidx(e, 70 + m)] = (unsigned short)b16r(a);
        } else if (i < 4055) {                // QMB[m]
            int m = i - 4052;
            float a = 0.f;
            for (int c = 0; c < 32; ++c) a += bq[c] * XMKs[m*32 + c];
            W[OFF_QMB + m] = a;
        } else if (i < 4663) {                // QG[e][k] -> fragment col 32+k
            int t2 = i - 4055, e = t2 / 19, k = t2 % 19;
            float a = 0.f;
            for (int c = 0; c < 32; ++c) a += wq[e*32 + c] * XGKs[k*32 + c];
            FH[fragidx(e, 32 + k)] = (unsigned short)b16r(a);
        } else if (i < 4682) {                // QGB[k]
            int k = i - 4663;
            float a = 0.f;
            for (int c = 0; c < 32; ++c) a += bq[c] * XGKs[k*32 + c];
            W[OFF_QGB + k] = a;
        } else if (i < 5043) {                // EGVB[k*20+j]
            int t2 = i - 4682, k = t2 / 19, j = t2 % 19;
            float a = 0.f;
            for (int c = 0; c < 32; ++c) a += XGVs[k*32 + c] * XBs[c*19 + j];
            W[EGVB + k*20 + j] = a;
        } else if (i < 5062) {                // EGVB pad col
            int k = i - 5043;
            W[EGVB + k*20 + 19] = 0.f;
        } else if (i < 5119) {                // MVB[m*19+j]
            int t2 = i - 5062, m = t2 / 19, j = t2 % 19;
            float a = 0.f;
            for (int c = 0; c < 32; ++c) a += XMVs[m*32 + c] * XBs[c*19 + j];
            W[OFF_MVB + t2] = a;
        } else {                              // CV[j]
            int j = i - 5119;
            float a = 0.f;
            for (int c = 0; c < 32; ++c) a += bv[c] * XBs[c*19 + j];
            for (int d = 0; d < 32; ++d) a += bo[d] * XA2s[d*19 + j];
            W[OFF_CV + j] = a;
        }
    }
}

// =====================================================================
// Main kernel — EXACT baseline (140.0 µs) version. R0 region reused 3x:
// cpred stage -> HF (H cols f32) -> out stage. All global input/output
// for the hot arrays is coalesced float4.
// =====================================================================
__global__ __launch_bounds__(256, 2) void main_k(
    const float* __restrict__ feat,
    const float* __restrict__ sflow,
    const float* __restrict__ cpred,
    const float* __restrict__ Wg,
    float* __restrict__ out)
{
    const CONST_AS float* W = to_const(Wg);
    const int t = threadIdx.x, lane = t & 63, wvi = t >> 6;
    const int pblk = blockIdx.x * 256;

    __shared__ __align__(16) float R0[32 * 264];            // CP / HF / OB
    __shared__ __align__(16) unsigned short OH[41 * 264];   // logits/O1/QM bf16
    __shared__ __align__(16) float GV[380];                 // GVB 19x20

    if (t < 95) ((float4*)GV)[t] = ((const float4*)(Wg + EGVB))[t];

    // ---- phase 0: stage cpred slab (coalesced) and pull rows ----
    {
        const float4* src = (const float4*)(cpred + (long)pblk * 19);
        float4* dst = (float4*)R0;
        dst[t] = src[t];
        dst[256 + t] = src[256 + t];
        dst[512 + t] = src[512 + t];
        dst[768 + t] = src[768 + t];
        if (t < 192) dst[1024 + t] = src[1024 + t];
    }
    __syncthreads();
    float cp[19];
#pragma unroll
    for (int k = 0; k < 19; ++k) cp[k] = R0[t*19 + k];
    float m1 = cp[0];
#pragma unroll
    for (int k = 1; k < 19; ++k) m1 = fmaxf(m1, cp[k]);
    float sum1 = 0.f;
#pragma unroll
    for (int k = 0; k < 19; ++k) { cp[k] = __expf(cp[k] - m1); sum1 += cp[k]; }
    float r1 = 1.f / sum1;
#pragma unroll
    for (int k = 0; k < 19; ++k) cp[k] *= r1;
    __syncthreads();   // cp regs filled; R0 free for HF

    // ---- loop-invariant B fragments (7 x 16B per lane) ----
    const short8* FH8 = (const short8*)(Wg + FRAGH);
    const short8* FL8 = (const short8*)(Wg + FRAGL);
    short8 bh0 = FH8[0*64 + lane], bh1 = FH8[1*64 + lane];
    short8 bh2 = FH8[2*64 + lane], bh3 = FH8[3*64 + lane];
    short8 bh4 = FH8[4*64 + lane];
    short8 bl0 = FL8[0*64 + lane], bl1 = FL8[1*64 + lane];

    const int n15 = lane & 15, q = lane >> 4;

    // ---- phase 1: MFMA, 4 tiles of 16 points per wave ----
#pragma unroll
    for (int tile = 0; tile < 4; ++tile) {
        const int p0 = wvi*64 + tile*16;
        const float* fr = feat + (long)(pblk + p0 + n15) * 32 + q*8;
        float xv[8];
        {
            float4 va = *(const float4*)fr;
            float4 vb = *(const float4*)(fr + 4);
            xv[0]=va.x; xv[1]=va.y; xv[2]=va.z; xv[3]=va.w;
            xv[4]=vb.x; xv[5]=vb.y; xv[6]=vb.z; xv[7]=vb.w;
        }
        short8 ah, al;
#pragma unroll
        for (int j = 0; j < 8; ++j) {
            unsigned h = b16r(xv[j]);
            ah[j] = (short)h;
            al[j] = (short)b16r(xv[j] - fromb(h));
        }
        f32x4 z4 = {0.f, 0.f, 0.f, 0.f};
        f32x4 aH0, aH1, a2_, a3_, a4_;
        aH0 = __builtin_amdgcn_mfma_f32_16x16x32_bf16(ah, bh0, z4, 0, 0, 0);
        aH0 = __builtin_amdgcn_mfma_f32_16x16x32_bf16(ah, bl0, aH0, 0, 0, 0);
        aH0 = __builtin_amdgcn_mfma_f32_16x16x32_bf16(al, bh0, aH0, 0, 0, 0);
        aH1 = __builtin_amdgcn_mfma_f32_16x16x32_bf16(ah, bh1, z4, 0, 0, 0);
        aH1 = __builtin_amdgcn_mfma_f32_16x16x32_bf16(ah, bl1, aH1, 0, 0, 0);
        aH1 = __builtin_amdgcn_mfma_f32_16x16x32_bf16(al, bh1, aH1, 0, 0, 0);
        a2_ = __builtin_amdgcn_mfma_f32_16x16x32_bf16(ah, bh2, z4, 0, 0, 0);
        a3_ = __builtin_amdgcn_mfma_f32_16x16x32_bf16(ah, bh3, z4, 0, 0, 0);
        a4_ = __builtin_amdgcn_mfma_f32_16x16x32_bf16(ah, bh4, z4, 0, 0, 0);

        *(f32x4*)&R0[(n15)      * 264 + p0 + q*4] = aH0;   // H cols 0..15
        *(f32x4*)&R0[(16 + n15) * 264 + p0 + q*4] = aH1;   // H cols 16..31
        {
            unsigned d0, d1;
            d0 = b16r(a2_[0]) | (b16r(a2_[1]) << 16);
            d1 = b16r(a2_[2]) | (b16r(a2_[3]) << 16);
            *(uint2*)&OH[(n15) * 264 + p0 + q*4] = make_uint2(d0, d1);
            d0 = b16r(a3_[0]) | (b16r(a3_[1]) << 16);
            d1 = b16r(a3_[2]) | (b16r(a3_[3]) << 16);
            *(uint2*)&OH[(16 + n15) * 264 + p0 + q*4] = make_uint2(d0, d1);
            if (n15 <= 8) {
                d0 = b16r(a4_[0]) | (b16r(a4_[1]) << 16);
                d1 = b16r(a4_[2]) | (b16r(a4_[3]) << 16);
                *(uint2*)&OH[(32 + n15) * 264 + p0 + q*4] = make_uint2(d0, d1);
            }
        }
    }
    __syncthreads();

    // =========== phase 2: epilogue, thread t = point p ===========
    const long p = pblk + t;

    float s0 = sflow[p*3 + 0], s1 = sflow[p*3 + 1], s2 = sflow[p*3 + 2];
    bool tmask = (s0 != 0.f) | (s1 != 0.f) | (s2 != 0.f);

    // ---- gate from mfma H (split-bf16, err ~1e-4) ----
    const float TH = 1.3862943611198906f;   // ln(4): sigmoid<0.8
    float sacc = W[OFF_B2];
#pragma unroll
    for (int c = 0; c < 32; ++c) {
        float a = R0[c*264 + t];
        float h = fmaxf(fmaf(a, W[OFF_BNS + c], W[OFF_BNH + c]), 0.f);
        sacc = fmaf(h, W[OFF_SW2 + c], sacc);
    }
    // margin safety net: exact f32 recompute for near-threshold points
    bool nearthr = fabsf(sacc - TH) < 1e-3f;
    if (__ballot(nearthr) != 0ULL) {
        float f[32];
        const float4* fp4 = (const float4*)(feat + p*32);
#pragma unroll
        for (int g = 0; g < 8; ++g) {
            float4 v = fp4[g];
            f[g*4+0]=v.x; f[g*4+1]=v.y; f[g*4+2]=v.z; f[g*4+3]=v.w;
        }
        float sr = W[OFF_B2];
        for (int c = 0; c < 32; ++c) {
            float a = 0.f;
#pragma unroll
            for (int e = 0; e < 32; ++e) a = fmaf(f[e], W[OFF_SW1 + c*32 + e], a);
            float h = fmaxf(fmaf(a, W[OFF_BNS + c], W[OFF_BNH + c]), 0.f);
            sr = fmaf(h, W[OFF_SW2 + c], sr);
        }
        sacc = nearthr ? sr : sacc;
    }
    bool valid = tmask && (sacc < TH);

    // ---- logits / qs from mfma U ----
    float qm0 = fromb(OH[38*264 + t]) + W[OFF_QMB + 0];
    float qm1 = fromb(OH[39*264 + t]) + W[OFF_QMB + 1];
    float qm2 = fromb(OH[40*264 + t]) + W[OFF_QMB + 2];
    float qs = s0*qm0 + s1*qm1 + s2*qm2;

    const float RS = 0.17677669529663687f;  // 1/sqrt(32)
    float l[19];
#pragma unroll
    for (int k = 0; k < 19; ++k)
        l[k] = (cp[k] * (fromb(OH[k*264 + t]) + W[OFF_QGB + k] + qs)) * RS;

    float m2 = l[0];
#pragma unroll
    for (int k = 1; k < 19; ++k) m2 = fmaxf(m2, l[k]);
    float sum2 = 0.f;
#pragma unroll
    for (int k = 0; k < 19; ++k) { l[k] = __expf(l[k] - m2); sum2 += l[k]; }
    float r2 = 1.f / sum2;
    float Sw = 0.f;
#pragma unroll
    for (int k = 0; k < 19; ++k) { l[k] = l[k] * r2 * cp[k]; Sw += l[k]; }

    // ---- o = U_A1 + BB;  a2 = CV + Sw*(sf@MVB) + w@GVB ----
    float rv[19];
    float c0 = Sw * s0, c1 = Sw * s1, c2 = Sw * s2;
    float vg = valid ? 1.f : 0.f;
    float a2v[19];
#pragma unroll
    for (int j = 0; j < 19; ++j)
        a2v[j] = W[OFF_CV + j] + c0 * W[OFF_MVB + j]
               + c1 * W[OFF_MVB + 19 + j] + c2 * W[OFF_MVB + 38 + j];
#pragma unroll
    for (int k = 0; k < 19; ++k) {
        float lk = l[k];
#pragma unroll
        for (int j = 0; j < 19; ++j) a2v[j] = fmaf(lk, GV[k*20 + j], a2v[j]);
    }
#pragma unroll
    for (int j = 0; j < 19; ++j)
        rv[j] = fmaf(vg, a2v[j], fromb(OH[(19 + j)*264 + t]) + W[OFF_BB + j]);

    // ---- phase 3: stage out rows -> coalesced float4 stores ----
    __syncthreads();   // all R0(HF) reads done
#pragma unroll
    for (int j = 0; j < 19; ++j) R0[t*19 + j] = rv[j];
    __syncthreads();
    {
        const float4* src = (const float4*)R0;
        float4* dst = (float4*)(out + (long)pblk * 19);
        dst[t] = src[t];
        dst[256 + t] = src[256 + t];
        dst[512 + t] = src[512 + t];
        dst[768 + t] = src[768 + t];
        if (t < 192) dst[1024 + t] = src[1024 + t];
    }
}

// =====================================================================
extern "C" void kernel_launch(void* const* d_in, const int* in_sizes, int n_in,
                              void* d_out, int out_size, void* d_ws, size_t ws_size,
                              hipStream_t stream) {
    const float* feat  = (const float*)d_in[0];
    const float* sflow = (const float*)d_in[1];
    const float* cpred = (const float*)d_in[2];
    const float* z     = (const float*)d_in[3];
    const float* sw1   = (const float*)d_in[4];
    const float* bn_g  = (const float*)d_in[5];
    const float* bn_b  = (const float*)d_in[6];
    const float* bn_m  = (const float*)d_in[7];
    const float* bn_v  = (const float*)d_in[8];
    const float* sw2   = (const float*)d_in[9];
    const float* sb2   = (const float*)d_in[10];
    const float* wq    = (const float*)d_in[11];
    const float* bq    = (const float*)d_in[12];
    const float* wk    = (const float*)d_in[13];
    const float* bk    = (const float*)d_in[14];  (void)bk;
    const float* wv    = (const float*)d_in[15];
    const float* bv    = (const float*)d_in[16];
    const float* wo    = (const float*)d_in[17];
    const float* bo    = (const float*)d_in[18];
    const float* wt    = (const float*)d_in[19];
    const float* bt    = (const float*)d_in[20];
    const float* wout  = (const float*)d_in[21];
    const float* bout  = (const float*)d_in[22];
    const float* wgen  = (const float*)d_in[23];
    const float* bgen  = (const float*)d_in[24];

    float* W = (float*)d_ws;

    hipLaunchKernelGGL(pre_par, dim3(PRE_BLOCKS), dim3(256), 0, stream,
                       z, sw1, bn_g, bn_b, bn_m, bn_v, sw2, sb2,
                       wq, bq, wk, wv, bv, wo, bo, wt, bt, wout, bout,
                       wgen, bgen, W);

    hipLaunchKernelGGL(main_k, dim3(512), dim3(256), 0, stream,
                       feat, sflow, cpred, W, (float*)d_out);
}

// Round 4
// 140.528 us; speedup vs baseline: 1.0530x; 1.0245x over previous
//
#include <hip/hip_runtime.h>

#define NPTS 131072

typedef __attribute__((ext_vector_type(8))) short short8;
typedef __attribute__((ext_vector_type(4))) float f32x4;

// ---------- d_ws layout (f32 dword indices) ----------
constexpr int OFF_SW1 = 0;      // 1024 SW1 TRANSPOSED [c*32+e] (gate recompute)
constexpr int OFF_BNS = 1024;   // 32
constexpr int OFF_BNH = 1056;   // 32
constexpr int OFF_SW2 = 1088;   // 32
constexpr int OFF_B2  = 1120;   // 1
constexpr int OFF_QGB = 1121;   // 19
constexpr int OFF_QMB = 1140;   // 3
constexpr int OFF_BB  = 1143;   // 19
constexpr int OFF_CV  = 1162;   // 19
constexpr int OFF_MVB = 1181;   // 57 [m*19+j]
constexpr int EGVB    = 1240;   // 380 = 19x20 padded GVB (16B-aligned)
constexpr int FRAGH   = 1620;   // 1280 dwords: B-frags hi [5][64][8] bf16
constexpr int FRAGL   = 2900;   // 512  dwords: B-frags lo [2][64][8] bf16 (SW1)
// intermediates:
constexpr int XA2 = 4020, XG = 4628, XMK = 5236, XMV = 5332;
constexpr int XGK = 5428, XGV = 6036, XB = 6644;

#define CONST_AS __attribute__((address_space(4)))
__device__ __forceinline__ const CONST_AS float* to_const(const float* p) {
    return (const CONST_AS float*)p;
}
__device__ __forceinline__ unsigned b16r(float x) {
    unsigned u = __float_as_uint(x);
    return (u + 0x7fffu + ((u >> 16) & 1u)) >> 16;
}
__device__ __forceinline__ float fromb(unsigned h) {
    return __uint_as_float(h << 16);
}
// inverse fragment map: value for (e=k-dim, col) -> FH[(T*64+l)*8+jj]
__device__ __forceinline__ int fragidx(int e, int col) {
    int T = col >> 4, l = (col & 15) + ((e >> 3) << 4), jj = e & 7;
    return (T * 64 + l) * 8 + jj;
}

// =====================================================================
// Precompute stage A (also emits SW1 hi/lo + A1 + pad fragments)
// =====================================================================
__global__ __launch_bounds__(256) void pre_a(
    const float* __restrict__ z,
    const float* __restrict__ sw1,
    const float* __restrict__ bn_gamma, const float* __restrict__ bn_beta,
    const float* __restrict__ bn_mean,  const float* __restrict__ bn_var,
    const float* __restrict__ sw2,      const float* __restrict__ sb2,
    const float* __restrict__ wk, const float* __restrict__ wv,
    const float* __restrict__ wt, const float* __restrict__ bt,
    const float* __restrict__ wout, const float* __restrict__ bout,
    const float* __restrict__ wgen, const float* __restrict__ bgen,
    float* __restrict__ W)
{
    int i = blockIdx.x * 256 + threadIdx.x;
    unsigned short* FH = (unsigned short*)(W + FRAGH);
    unsigned short* FL = (unsigned short*)(W + FRAGL);
    if (i < 1024) {                       // SW1T[c*32+e] = sw1[e*32+c]
        W[OFF_SW1 + i] = sw1[(i & 31) * 32 + (i >> 5)];
    } else if (i < 1632) {                // A1 -> fragment, A2 -> interm
        int t = i - 1024, e = t / 19, j = t % 19;
        float a1 = 0.f, a2 = 0.f;
        for (int d = 0; d < 32; ++d) {
            float w_ = wout[d*19 + j];
            a1 += wt[e*32 + d] * w_;
            a2 += wt[(32 + e)*32 + d] * w_;
        }
        FH[fragidx(e, 51 + j)] = (unsigned short)b16r(a1);
        W[XA2 + t] = a2;
    } else if (i < 2240) {                // G[k*32+e]
        int t = i - 1632, k = t >> 5, e = t & 31;
        float g = bgen[e];
        for (int d = 0; d < 16; ++d) g += z[d] * wgen[d*32 + e];
        W[XG + t] = g + wgen[(16 + k)*32 + e];
    } else if (i < 2336) {                // Mk, Mv
        int t = i - 2240, m = t >> 5, c = t & 31;
        float a = 0.f, b = 0.f;
        for (int e = 0; e < 32; ++e) {
            float wsr = wgen[(35 + m)*32 + e];
            a += wsr * wk[e*32 + c];
            b += wsr * wv[e*32 + c];
        }
        W[XMK + t] = a; W[XMV + t] = b;
    } else if (i < 2368) {                // BN fold + SW2
        int t = i - 2336;
        float scale = bn_gamma[t] / sqrtf(bn_var[t] + 1e-4f);
        W[OFF_BNS + t] = scale;
        W[OFF_BNH + t] = bn_beta[t] - bn_mean[t] * scale;
        W[OFF_SW2 + t] = sw2[t];
    } else if (i < 2387) {                // BB
        int t = i - 2368;
        float a = bout[t];
        for (int d = 0; d < 32; ++d) a += bt[d] * wout[d*19 + t];
        W[OFF_BB + t] = a;
    } else if (i == 2387) {
        W[OFF_B2] = sb2[0];
    } else if (i < 3412) {                // SW1 hi fragments (tiles 0-1)
        int idx = i - 2388;
        int T = idx >> 9, rem = idx & 511, l = rem >> 3, j = rem & 7;
        int e = ((l >> 4) << 3) + j, col = 16*T + (l & 15);
        FH[(T*64 + l)*8 + j] = (unsigned short)b16r(sw1[e*32 + col]);
    } else if (i < 4436) {                // SW1 lo fragments
        int idx = i - 3412;
        int T = idx >> 9, rem = idx & 511, l = rem >> 3, j = rem & 7;
        int e = ((l >> 4) << 3) + j, col = 16*T + (l & 15);
        float v = sw1[e*32 + col];
        FL[(T*64 + l)*8 + j] = (unsigned short)b16r(v - fromb(b16r(v)));
    } else if (i < 4660) {                // pad cols 73..79 of tile 4 = 0
        int idx = i - 4436;
        int col = 73 + idx / 32, rem = idx & 31, q = rem >> 3, j2 = rem & 7;
        int l = (col & 15) + (q << 4);
        FH[(4*64 + l)*8 + j2] = 0;
    }
}

// =====================================================================
// Precompute stage B (also emits QM fragments)
// =====================================================================
__global__ __launch_bounds__(256) void pre_b(
    const float* __restrict__ wq, const float* __restrict__ bq,
    const float* __restrict__ wk, const float* __restrict__ wv,
    const float* __restrict__ wo,
    float* __restrict__ W)
{
    int i = blockIdx.x * 256 + threadIdx.x;
    unsigned short* FH = (unsigned short*)(W + FRAGH);
    if (i < 608) {                        // Gk, Gv  [k*32+c]
        int k = i >> 5, c = i & 31;
        float a = 0.f, b = 0.f;
        for (int e = 0; e < 32; ++e) {
            float g = W[XG + k*32 + e];
            a += g * wk[e*32 + c];
            b += g * wv[e*32 + c];
        }
        W[XGK + i] = a; W[XGV + i] = b;
    } else if (i < 1216) {                // B[c*19+j] = wo @ A2
        int t = i - 608, c = t / 19, j = t % 19;
        float a = 0.f;
        for (int d = 0; d < 32; ++d) a += wo[c*32 + d] * W[XA2 + d*19 + j];
        W[XB + t] = a;
    } else if (i < 1312) {                // QM[e][m] -> fragment col 70+m
        int t = i - 1216, e = t / 3, m = t % 3;
        float a = 0.f;
        for (int c = 0; c < 32; ++c) a += wq[e*32 + c] * W[XMK + m*32 + c];
        FH[fragidx(e, 70 + m)] = (unsigned short)b16r(a);
    } else if (i < 1315) {                // QMB[m]
        int m = i - 1312;
        float a = 0.f;
        for (int c = 0; c < 32; ++c) a += bq[c] * W[XMK + m*32 + c];
        W[OFF_QMB + m] = a;
    }
}

// =====================================================================
// Precompute stage C (also emits QG fragments)
// =====================================================================
__global__ __launch_bounds__(256) void pre_c(
    const float* __restrict__ wq, const float* __restrict__ bq,
    const float* __restrict__ bv, const float* __restrict__ bo,
    float* __restrict__ W)
{
    int i = blockIdx.x * 256 + threadIdx.x;
    unsigned short* FH = (unsigned short*)(W + FRAGH);
    if (i < 608) {                        // QG[e][k] -> fragment col 32+k
        int e = i / 19, k = i % 19;
        float a = 0.f;
        for (int c = 0; c < 32; ++c) a += wq[e*32 + c] * W[XGK + k*32 + c];
        FH[fragidx(e, 32 + k)] = (unsigned short)b16r(a);
    } else if (i < 627) {                 // QGB[k]
        int k = i - 608;
        float a = 0.f;
        for (int c = 0; c < 32; ++c) a += bq[c] * W[XGK + k*32 + c];
        W[OFF_QGB + k] = a;
    } else if (i < 988) {                 // EGVB[k*20+j]
        int t = i - 627, k = t / 19, j = t % 19;
        float a = 0.f;
        for (int c = 0; c < 32; ++c) a += W[XGV + k*32 + c] * W[XB + c*19 + j];
        W[EGVB + k*20 + j] = a;
    } else if (i < 1007) {                // EGVB pad col
        int k = i - 988;
        W[EGVB + k*20 + 19] = 0.f;
    } else if (i < 1064) {                // MVB[m*19+j]
        int t = i - 1007, m = t / 19, j = t % 19;
        float a = 0.f;
        for (int c = 0; c < 32; ++c) a += W[XMV + m*32 + c] * W[XB + c*19 + j];
        W[OFF_MVB + t] = a;
    } else if (i < 1083) {                // CV[j]
        int j = i - 1064;
        float a = 0.f;
        for (int c = 0; c < 32; ++c) a += bv[c] * W[XB + c*19 + j];
        for (int d = 0; d < 32; ++d) a += bo[d] * W[XA2 + d*19 + j];
        W[OFF_CV + j] = a;
    }
}

// =====================================================================
// Main kernel. R0 region reused 3x: cpred stage -> HF (H cols f32) -> out
// stage. All global input/output for the hot arrays is coalesced float4.
// =====================================================================
__global__ __launch_bounds__(256, 2) void main_k(
    const float* __restrict__ feat,
    const float* __restrict__ sflow,
    const float* __restrict__ cpred,
    const float* __restrict__ Wg,
    float* __restrict__ out)
{
    const CONST_AS float* W = to_const(Wg);
    const int t = threadIdx.x, lane = t & 63, wvi = t >> 6;
    const int pblk = blockIdx.x * 256;

    __shared__ __align__(16) float R0[32 * 264];            // CP / HF / OB
    __shared__ __align__(16) unsigned short OH[41 * 264];   // logits/O1/QM bf16
    __shared__ __align__(16) float GV[380];                 // GVB 19x20

    if (t < 95) ((float4*)GV)[t] = ((const float4*)(Wg + EGVB))[t];

    // ---- phase 0: stage cpred slab (coalesced) and pull rows ----
    {
        const float4* src = (const float4*)(cpred + (long)pblk * 19);
        float4* dst = (float4*)R0;
        dst[t] = src[t];
        dst[256 + t] = src[256 + t];
        dst[512 + t] = src[512 + t];
        dst[768 + t] = src[768 + t];
        if (t < 192) dst[1024 + t] = src[1024 + t];
    }
    __syncthreads();
    float cp[19];
#pragma unroll
    for (int k = 0; k < 19; ++k) cp[k] = R0[t*19 + k];
    float m1 = cp[0];
#pragma unroll
    for (int k = 1; k < 19; ++k) m1 = fmaxf(m1, cp[k]);
    float sum1 = 0.f;
#pragma unroll
    for (int k = 0; k < 19; ++k) { cp[k] = __expf(cp[k] - m1); sum1 += cp[k]; }
    float r1 = 1.f / sum1;
#pragma unroll
    for (int k = 0; k < 19; ++k) cp[k] *= r1;
    __syncthreads();   // cp regs filled; R0 free for HF

    // ---- loop-invariant B fragments (7 x 16B per lane) ----
    const short8* FH8 = (const short8*)(Wg + FRAGH);
    const short8* FL8 = (const short8*)(Wg + FRAGL);
    short8 bh0 = FH8[0*64 + lane], bh1 = FH8[1*64 + lane];
    short8 bh2 = FH8[2*64 + lane], bh3 = FH8[3*64 + lane];
    short8 bh4 = FH8[4*64 + lane];
    short8 bl0 = FL8[0*64 + lane], bl1 = FL8[1*64 + lane];

    const int n15 = lane & 15, q = lane >> 4;

    // ---- phase 1: MFMA, 4 tiles of 16 points per wave ----
#pragma unroll
    for (int tile = 0; tile < 4; ++tile) {
        const int p0 = wvi*64 + tile*16;
        const float* fr = feat + (long)(pblk + p0 + n15) * 32 + q*8;
        float xv[8];
        {
            float4 va = *(const float4*)fr;
            float4 vb = *(const float4*)(fr + 4);
            xv[0]=va.x; xv[1]=va.y; xv[2]=va.z; xv[3]=va.w;
            xv[4]=vb.x; xv[5]=vb.y; xv[6]=vb.z; xv[7]=vb.w;
        }
        short8 ah, al;
#pragma unroll
        for (int j = 0; j < 8; ++j) {
            unsigned h = b16r(xv[j]);
            ah[j] = (short)h;
            al[j] = (short)b16r(xv[j] - fromb(h));
        }
        f32x4 z4 = {0.f, 0.f, 0.f, 0.f};
        f32x4 aH0, aH1, a2_, a3_, a4_;
        aH0 = __builtin_amdgcn_mfma_f32_16x16x32_bf16(ah, bh0, z4, 0, 0, 0);
        aH0 = __builtin_amdgcn_mfma_f32_16x16x32_bf16(ah, bl0, aH0, 0, 0, 0);
        aH0 = __builtin_amdgcn_mfma_f32_16x16x32_bf16(al, bh0, aH0, 0, 0, 0);
        aH1 = __builtin_amdgcn_mfma_f32_16x16x32_bf16(ah, bh1, z4, 0, 0, 0);
        aH1 = __builtin_amdgcn_mfma_f32_16x16x32_bf16(ah, bl1, aH1, 0, 0, 0);
        aH1 = __builtin_amdgcn_mfma_f32_16x16x32_bf16(al, bh1, aH1, 0, 0, 0);
        a2_ = __builtin_amdgcn_mfma_f32_16x16x32_bf16(ah, bh2, z4, 0, 0, 0);
        a3_ = __builtin_amdgcn_mfma_f32_16x16x32_bf16(ah, bh3, z4, 0, 0, 0);
        a4_ = __builtin_amdgcn_mfma_f32_16x16x32_bf16(ah, bh4, z4, 0, 0, 0);

        *(f32x4*)&R0[(n15)      * 264 + p0 + q*4] = aH0;   // H cols 0..15
        *(f32x4*)&R0[(16 + n15) * 264 + p0 + q*4] = aH1;   // H cols 16..31
        {
            unsigned d0, d1;
            d0 = b16r(a2_[0]) | (b16r(a2_[1]) << 16);
            d1 = b16r(a2_[2]) | (b16r(a2_[3]) << 16);
            *(uint2*)&OH[(n15) * 264 + p0 + q*4] = make_uint2(d0, d1);
            d0 = b16r(a3_[0]) | (b16r(a3_[1]) << 16);
            d1 = b16r(a3_[2]) | (b16r(a3_[3]) << 16);
            *(uint2*)&OH[(16 + n15) * 264 + p0 + q*4] = make_uint2(d0, d1);
            if (n15 <= 8) {
                d0 = b16r(a4_[0]) | (b16r(a4_[1]) << 16);
                d1 = b16r(a4_[2]) | (b16r(a4_[3]) << 16);
                *(uint2*)&OH[(32 + n15) * 264 + p0 + q*4] = make_uint2(d0, d1);
            }
        }
    }
    __syncthreads();

    // =========== phase 2: epilogue, thread t = point p ===========
    const long p = pblk + t;

    float s0 = sflow[p*3 + 0], s1 = sflow[p*3 + 1], s2 = sflow[p*3 + 2];
    bool tmask = (s0 != 0.f) | (s1 != 0.f) | (s2 != 0.f);

    // ---- gate from mfma H (split-bf16, err ~1e-4) ----
    const float TH = 1.3862943611198906f;   // ln(4): sigmoid<0.8
    float sacc = W[OFF_B2];
#pragma unroll
    for (int c = 0; c < 32; ++c) {
        float a = R0[c*264 + t];
        float h = fmaxf(fmaf(a, W[OFF_BNS + c], W[OFF_BNH + c]), 0.f);
        sacc = fmaf(h, W[OFF_SW2 + c], sacc);
    }
    // margin safety net: exact f32 recompute for near-threshold points
    bool nearthr = fabsf(sacc - TH) < 1e-3f;
    if (__ballot(nearthr) != 0ULL) {
        float f[32];
        const float4* fp4 = (const float4*)(feat + p*32);
#pragma unroll
        for (int g = 0; g < 8; ++g) {
            float4 v = fp4[g];
            f[g*4+0]=v.x; f[g*4+1]=v.y; f[g*4+2]=v.z; f[g*4+3]=v.w;
        }
        float sr = W[OFF_B2];
        for (int c = 0; c < 32; ++c) {
            float a = 0.f;
#pragma unroll
            for (int e = 0; e < 32; ++e) a = fmaf(f[e], W[OFF_SW1 + c*32 + e], a);
            float h = fmaxf(fmaf(a, W[OFF_BNS + c], W[OFF_BNH + c]), 0.f);
            sr = fmaf(h, W[OFF_SW2 + c], sr);
        }
        sacc = nearthr ? sr : sacc;
    }
    bool valid = tmask && (sacc < TH);

    // ---- logits / qs from mfma U ----
    float qm0 = fromb(OH[38*264 + t]) + W[OFF_QMB + 0];
    float qm1 = fromb(OH[39*264 + t]) + W[OFF_QMB + 1];
    float qm2 = fromb(OH[40*264 + t]) + W[OFF_QMB + 2];
    float qs = s0*qm0 + s1*qm1 + s2*qm2;

    const float RS = 0.17677669529663687f;  // 1/sqrt(32)
    float l[19];
#pragma unroll
    for (int k = 0; k < 19; ++k)
        l[k] = (cp[k] * (fromb(OH[k*264 + t]) + W[OFF_QGB + k] + qs)) * RS;

    float m2 = l[0];
#pragma unroll
    for (int k = 1; k < 19; ++k) m2 = fmaxf(m2, l[k]);
    float sum2 = 0.f;
#pragma unroll
    for (int k = 0; k < 19; ++k) { l[k] = __expf(l[k] - m2); sum2 += l[k]; }
    float r2 = 1.f / sum2;
    float Sw = 0.f;
#pragma unroll
    for (int k = 0; k < 19; ++k) { l[k] = l[k] * r2 * cp[k]; Sw += l[k]; }

    // ---- o = U_A1 + BB;  a2 = CV + Sw*(sf@MVB) + w@GVB ----
    float rv[19];
    float c0 = Sw * s0, c1 = Sw * s1, c2 = Sw * s2;
    float vg = valid ? 1.f : 0.f;
    float a2v[19];
#pragma unroll
    for (int j = 0; j < 19; ++j)
        a2v[j] = W[OFF_CV + j] + c0 * W[OFF_MVB + j]
               + c1 * W[OFF_MVB + 19 + j] + c2 * W[OFF_MVB + 38 + j];
#pragma unroll
    for (int k = 0; k < 19; ++k) {
        float lk = l[k];
#pragma unroll
        for (int j = 0; j < 19; ++j) a2v[j] = fmaf(lk, GV[k*20 + j], a2v[j]);
    }
#pragma unroll
    for (int j = 0; j < 19; ++j)
        rv[j] = fmaf(vg, a2v[j], fromb(OH[(19 + j)*264 + t]) + W[OFF_BB + j]);

    // ---- phase 3: stage out rows -> coalesced float4 stores ----
    __syncthreads();   // all R0(HF) reads done
#pragma unroll
    for (int j = 0; j < 19; ++j) R0[t*19 + j] = rv[j];
    __syncthreads();
    {
        const float4* src = (const float4*)R0;
        float4* dst = (float4*)(out + (long)pblk * 19);
        dst[t] = src[t];
        dst[256 + t] = src[256 + t];
        dst[512 + t] = src[512 + t];
        dst[768 + t] = src[768 + t];
        if (t < 192) dst[1024 + t] = src[1024 + t];
    }
}

// =====================================================================
extern "C" void kernel_launch(void* const* d_in, const int* in_sizes, int n_in,
                              void* d_out, int out_size, void* d_ws, size_t ws_size,
                              hipStream_t stream) {
    const float* feat  = (const float*)d_in[0];
    const float* sflow = (const float*)d_in[1];
    const float* cpred = (const float*)d_in[2];
    const float* z     = (const float*)d_in[3];
    const float* sw1   = (const float*)d_in[4];
    const float* bn_g  = (const float*)d_in[5];
    const float* bn_b  = (const float*)d_in[6];
    const float* bn_m  = (const float*)d_in[7];
    const float* bn_v  = (const float*)d_in[8];
    const float* sw2   = (const float*)d_in[9];
    const float* sb2   = (const float*)d_in[10];
    const float* wq    = (const float*)d_in[11];
    const float* bq    = (const float*)d_in[12];
    const float* wk    = (const float*)d_in[13];
    const float* bk    = (const float*)d_in[14];  (void)bk;
    const float* wv    = (const float*)d_in[15];
    const float* bv    = (const float*)d_in[16];
    const float* wo    = (const float*)d_in[17];
    const float* bo    = (const float*)d_in[18];
    const float* wt    = (const float*)d_in[19];
    const float* bt    = (const float*)d_in[20];
    const float* wout  = (const float*)d_in[21];
    const float* bout  = (const float*)d_in[22];
    const float* wgen  = (const float*)d_in[23];
    const float* bgen  = (const float*)d_in[24];

    float* W = (float*)d_ws;

    hipLaunchKernelGGL(pre_a, dim3(19), dim3(256), 0, stream,
                       z, sw1, bn_g, bn_b, bn_m, bn_v, sw2, sb2,
                       wk, wv, wt, bt, wout, bout, wgen, bgen, W);
    hipLaunchKernelGGL(pre_b, dim3(6), dim3(256), 0, stream,
                       wq, bq, wk, wv, wo, W);
    hipLaunchKernelGGL(pre_c, dim3(5), dim3(256), 0, stream,
                       wq, bq, bv, bo, W);

    hipLaunchKernelGGL(main_k, dim3(512), dim3(256), 0, stream,
                       feat, sflow, cpred, W, (float*)d_out);
}